// Round 14
// baseline (936.475 us; speedup 1.0000x reference)
//
#include <hip/hip_runtime.h>
#include <cstdint>
#include <cstddef>

// ---------------- problem constants ----------------
#define NN 30000        // nodes
#define NE 400000       // edges per scatter set
#define EG (NE + NN)    // GAT edges incl self loops
#define NSETS 5
#define NCLS 10
#define BN_EPS 1e-5f

// bucketed CSR build
#define NBKT 118
#define CHUNK 4096
#define NWG_SET 98
#define NWG_GAT 105
#define NWGMAX 105
#define NBLK_BIN (5 * NWG_SET + NWG_GAT)   // 595
#define NBLK_SORT (6 * NBKT)               // 708
#define LIN_B 469
#define GM_B 469
#define COMB_GRID (GM_B * 17)              // 7973: every 17th block is GM, rest gat

typedef __bf16 bf16x8 __attribute__((ext_vector_type(8)));
typedef float  f32x4  __attribute__((ext_vector_type(4)));

// ---------------- workspace layout (bytes) ----------------
constexpr size_t alg(size_t x) { return (x + 255) & ~size_t(255); }
constexpr size_t OFF_U1    = 0;                                        // xb | xcur5
constexpr size_t OFF_HB    = OFF_U1   + alg((size_t)5 * NN * 128 * 2);
constexpr size_t OFF_X2    = OFF_HB   + alg((size_t)NN * 128 * 2);
constexpr size_t OFF_AGG   = OFF_X2   + alg((size_t)NN * 128 * 4);     // aggA
constexpr size_t OFF_GOUT  = OFF_AGG  + alg((size_t)NN * 512 * 2);     // CSR staging -> tmp4 -> aggB
constexpr size_t OFF_WT    = OFF_GOUT + alg((size_t)NN * 512 * 2);
constexpr size_t OFF_WATT  = OFF_WT   + alg((size_t)11 * 65536 * 2);
constexpr size_t OFF_OFF6  = OFF_WATT + alg((size_t)5 * 2 * 4 * 128 * 4);
constexpr size_t OFF_SPP   = OFF_OFF6 + alg((size_t)6 * (NN + 1) * 4);
constexpr size_t OFF_GSRC  = OFF_SPP  + alg((size_t)NSETS * NE * 8);
constexpr size_t OFF_CNT   = OFF_GSRC + alg((size_t)EG * 4);
constexpr size_t OFF_AS5   = OFF_CNT  + alg((size_t)12 * NN * 4);
constexpr size_t OFF_AD5   = OFF_AS5  + alg((size_t)5 * NN * 4 * 4);
constexpr size_t WS_NEED   = OFF_AD5  + alg((size_t)5 * NN * 4 * 4);   // ~149 MB

// ---------------- helpers ----------------
__device__ __forceinline__ float lrelu02(float v) { return v > 0.f ? v : 0.2f * v; }
__device__ __forceinline__ float eluf(float v)    { return v > 0.f ? v : __expf(v) - 1.f; }
__device__ __forceinline__ float bf2f(unsigned u) {
    union { unsigned i; float f; } c; c.i = u << 16; return c.f;
}
__device__ __forceinline__ unsigned short f2bf(float f) {
    union { float f; unsigned i; } c; c.f = f;
    unsigned u = c.i + 0x7FFFu + ((c.i >> 16) & 1u);
    return (unsigned short)(u >> 16);
}
__device__ __forceinline__ void gload_lds16(const void* g, void* l) {
    __builtin_amdgcn_global_load_lds(
        (const __attribute__((address_space(1))) void*)(uintptr_t)g,
        (__attribute__((address_space(3))) void*)(unsigned)(uintptr_t)l,
        16, 0, 0);
}

__device__ __forceinline__ void chunk_map(int blk, int& g, int& wg, int& e0, int& e1) {
    if (blk < 5 * NWG_SET) { g = blk / NWG_SET; wg = blk - g * NWG_SET; }
    else                   { g = 5;             wg = blk - 5 * NWG_SET; }
    e0 = wg * CHUNK;
    e1 = min(e0 + CHUNK, (g < 5) ? NE : EG);
}

// ---------------- prep1: hist | convx | transW | wattk ----------------
#define PREP_CVX_B 1024
#define PREP_TRW_B 512
#define PREP_WAT_B 20
#define PREP_HIST_B NBLK_BIN
#define PREP_GRID (PREP_CVX_B + PREP_TRW_B + PREP_WAT_B + PREP_HIST_B)

__global__ void prep1(const int* __restrict__ scat_idx, const int* __restrict__ edge_ix,
                      int* __restrict__ bh,
                      const float* __restrict__ x, unsigned short* __restrict__ xb,
                      const float* __restrict__ lin_W, const float* __restrict__ gat_W,
                      const float* __restrict__ mlp_W,
                      unsigned short* __restrict__ linWT, unsigned short* __restrict__ gatWT,
                      unsigned short* __restrict__ mlpWT,
                      const float* __restrict__ att_src, const float* __restrict__ att_dst,
                      float* __restrict__ watt) {
    __shared__ int h[NBKT];
    const int b = blockIdx.x;
    if (b < PREP_CVX_B) {
        const int total = NN * 512 / 4;
        for (int i = b * 256 + threadIdx.x; i < total; i += PREP_CVX_B * 256) {
            float4 v = *(const float4*)(x + (size_t)i * 4);
            ushort4 o;
            o.x = f2bf(v.x); o.y = f2bf(v.y); o.z = f2bf(v.z); o.w = f2bf(v.w);
            *(ushort4*)(xb + (size_t)i * 4) = o;
        }
    } else if (b < PREP_CVX_B + PREP_TRW_B) {
        const int bb = b - PREP_CVX_B;
        const int total = 65536 + 2 * 327680;
        for (int i = bb * 256 + threadIdx.x; i < total; i += PREP_TRW_B * 256) {
            if (i < 65536) {
                int n = i >> 9, k = i & 511;
                linWT[i] = f2bf(lin_W[(size_t)k * 128 + n]);
            } else if (i < 65536 + 327680) {
                int li = i - 65536;
                int st = li >> 16, r = li & 65535;
                int n = r >> 7, k = r & 127;
                gatWT[li] = f2bf(gat_W[(size_t)st * 65536 + (size_t)k * 512 + n]);
            } else {
                int li = i - 65536 - 327680;
                int st = li >> 16, r = li & 65535;
                int n = r >> 9, k = r & 511;
                mlpWT[li] = f2bf(mlp_W[(size_t)st * 65536 + (size_t)k * 128 + n]);
            }
        }
    } else if (b < PREP_CVX_B + PREP_TRW_B + PREP_WAT_B) {
        const int tid = (b - PREP_CVX_B - PREP_TRW_B) * 256 + threadIdx.x;
        if (tid < 5120) {
            int k = tid & 127, hh = (tid >> 7) & 3, tt = (tid >> 9) & 1, i = tid >> 10;
            const float* att = (tt == 0 ? att_src : att_dst) + ((size_t)i * 4 + hh) * 128;
            const float* Wr  = gat_W + ((size_t)i * 128 + k) * 512 + hh * 128;
            float s = 0.f;
            #pragma unroll 8
            for (int c = 0; c < 128; ++c) s = fmaf(Wr[c], att[c], s);
            watt[tid] = s;
        }
    } else {
        const int blk = b - (PREP_CVX_B + PREP_TRW_B + PREP_WAT_B);
        int g, wg, e0, e1;
        chunk_map(blk, g, wg, e0, e1);
        for (int i = threadIdx.x; i < NBKT; i += 256) h[i] = 0;
        __syncthreads();
        if (g < 5) {
            const int* dsts = scat_idx + (size_t)g * 2 * NE + NE;
            for (int e = e0 + threadIdx.x; e < e1; e += 256)
                atomicAdd(&h[dsts[e] >> 8], 1);
        } else {
            for (int e = e0 + threadIdx.x; e < e1; e += 256) {
                int d = (e < NE) ? edge_ix[NE + e] : (e - NE);
                atomicAdd(&h[d >> 8], 1);
            }
        }
        __syncthreads();
        for (int i = threadIdx.x; i < NBKT; i += 256)
            bh[(size_t)(g * NBKT + i) * NWGMAX + wg] = h[i];
    }
}

// ---------------- bktscan ----------------
__global__ void bktscan(const int* __restrict__ bh, int* __restrict__ bb, int* __restrict__ off6) {
    const int g = blockIdx.x;
    const int t = threadIdx.x;
    const int nwg = (g < 5) ? NWG_SET : NWG_GAT;
    __shared__ int s[128];
    int tot = 0;
    if (t < NBKT) {
        const int* p = bh + (size_t)(g * NBKT + t) * NWGMAX;
        for (int w = 0; w < nwg; ++w) tot += p[w];
    }
    s[t] = tot;
    __syncthreads();
    for (int d = 1; d < 128; d <<= 1) {
        int u = (t >= d) ? s[t - d] : 0;
        __syncthreads();
        s[t] += u;
        __syncthreads();
    }
    if (t < NBKT) bb[g * 132 + t] = s[t] - tot;
    if (t == NBKT - 1) {
        bb[g * 132 + NBKT] = s[t];
        off6[g * (NN + 1) + NN] = s[t];
    }
}

// ---------------- wgscan ----------------
__global__ void wgscan(const int* __restrict__ bb, int* __restrict__ bh) {
    const int gb = blockIdx.x;
    const int g = gb / NBKT, bk = gb - g * NBKT;
    __shared__ int s[128];
    const int t = threadIdx.x;
    const int nwg = (g < 5) ? NWG_SET : NWG_GAT;
    int v = (t < nwg) ? bh[(size_t)gb * NWGMAX + t] : 0;
    s[t] = v;
    __syncthreads();
    for (int d = 1; d < 128; d <<= 1) {
        int u = (t >= d) ? s[t - d] : 0;
        __syncthreads();
        s[t] += u;
        __syncthreads();
    }
    const int base = bb[g * 132 + bk];
    if (t < nwg) bh[(size_t)gb * NWGMAX + t] = base + (s[t] - v);
}

// ---------------- staging helper ----------------
template<int ROWS>
__device__ __forceinline__ void stage64(const unsigned short* __restrict__ src, int ld,
                                        int row0, int maxrow, int k0, char* lds, int t) {
    const int wave = t >> 6, lane = t & 63;
    const int sub = lane >> 3;
    const int kch = (lane & 7) ^ sub;
    for (int j = wave; j < ROWS / 8; j += 4) {
        int grow = row0 + j * 8 + sub;
        if (grow > maxrow) grow = maxrow;
        gload_lds16(src + (size_t)grow * ld + k0 + kch * 8, lds + j * 1024);
    }
}

// ---------------- binlin: binP | mgemm_lin ----------------
__global__ void __launch_bounds__(256) binlin(const int* __restrict__ scat_idx, const float* __restrict__ scat_w,
                                              const int* __restrict__ edge_ix, const int* __restrict__ pos,
                                              int2* __restrict__ stg_sp, int* __restrict__ stg_g,
                                              const unsigned short* __restrict__ A,
                                              const unsigned short* __restrict__ BT,
                                              const float* __restrict__ bias,
                                              unsigned short* __restrict__ outb,
                                              float* __restrict__ x2) {
    __shared__ __align__(16) char shm[25600];
    const int t = threadIdx.x;
    if (blockIdx.x < LIN_B) {
        constexpr int K = 512, NC = 128;
        char* As = shm;
        char* Bs = shm + 8192;
        const int wave = t >> 6, lane = t & 63;
        const int bm = blockIdx.x * 64;
        const int wr = (wave >> 1) * 32, wc = (wave & 1) * 64;
        const int l15 = lane & 15, l4 = lane >> 4;
        const int rsw = (l15 & 7) << 4;
        f32x4 acc[2][4] = {};
        for (int kt = 0; kt < K; kt += 64) {
            stage64<64>(A, K, bm, NN - 1, kt, As, t);
            stage64<128>(BT, K, 0, NC - 1, kt, Bs, t);
            __syncthreads();
            #pragma unroll
            for (int kk = 0; kk < 2; ++kk) {
                bf16x8 af[2], bf[4];
                const int koff = kk * 64 + l4 * 16;
                #pragma unroll
                for (int fm = 0; fm < 2; ++fm)
                    af[fm] = *(const bf16x8*)(As + (wr + fm * 16 + l15) * 128 + (koff ^ rsw));
                #pragma unroll
                for (int fn = 0; fn < 4; ++fn)
                    bf[fn] = *(const bf16x8*)(Bs + (wc + fn * 16 + l15) * 128 + (koff ^ rsw));
                #pragma unroll
                for (int fm = 0; fm < 2; ++fm)
                    #pragma unroll
                    for (int fn = 0; fn < 4; ++fn)
                        acc[fm][fn] = __builtin_amdgcn_mfma_f32_16x16x32_bf16(af[fm], bf[fn], acc[fm][fn], 0, 0, 0);
            }
            __syncthreads();
        }
        #pragma unroll
        for (int fn = 0; fn < 4; ++fn) {
            const int c = wc + fn * 16 + l15;
            const float bias_c = bias[c];
            #pragma unroll
            for (int fm = 0; fm < 2; ++fm) {
                #pragma unroll
                for (int rg = 0; rg < 4; ++rg) {
                    int r = bm + wr + fm * 16 + l4 * 4 + rg;
                    if (r < NN) {
                        float v = acc[fm][fn][rg] + bias_c;
                        outb[(size_t)r * NC + c] = f2bf(v);
                        x2[(size_t)r * NC + c] = v;
                    }
                }
            }
        }
    } else {
        int* lpos = (int*)shm;
        int* lcur = lpos + NBKT;
        int g, wg, e0, e1;
        chunk_map(blockIdx.x - LIN_B, g, wg, e0, e1);
        for (int i = t; i < NBKT; i += 256) {
            lpos[i] = pos[(size_t)(g * NBKT + i) * NWGMAX + wg];
            lcur[i] = 0;
        }
        __syncthreads();
        if (g < 5) {
            const int* si = scat_idx + (size_t)g * 2 * NE;
            const float* sw = scat_w + (size_t)g * NE;
            for (int e = e0 + t; e < e1; e += 256) {
                int src = si[e], d = si[NE + e];
                int r = atomicAdd(&lcur[d >> 8], 1);
                int2 pk; pk.x = src | (d << 15); pk.y = __float_as_int(sw[e]);
                stg_sp[(size_t)g * NE + lpos[d >> 8] + r] = pk;
            }
        } else {
            for (int e = e0 + t; e < e1; e += 256) {
                int src, d;
                if (e < NE) { src = edge_ix[e]; d = edge_ix[NE + e]; }
                else        { src = e - NE;     d = src; }
                int r = atomicAdd(&lcur[d >> 8], 1);
                stg_g[lpos[d >> 8] + r] = src | (d << 15);
            }
        }
    }
}

// ---------------- sortP ----------------
__global__ void __launch_bounds__(256) sortP(const int* __restrict__ bb,
                                             const int2* __restrict__ stg_sp, const int* __restrict__ stg_g,
                                             int2* __restrict__ spp, int* __restrict__ g_src,
                                             int* __restrict__ off6) {
    __shared__ int lcnt[256];
    __shared__ int loff[257];
    const int gb = blockIdx.x;
    const int g = gb / NBKT, bk = gb - g * NBKT;
    const int n0 = bk << 8;
    const int nlen = min(256, NN - n0);
    const int base = bb[g * 132 + bk];
    const int end  = bb[g * 132 + bk + 1];
    const int t = threadIdx.x;
    lcnt[t] = 0;
    __syncthreads();
    if (g < 5) {
        for (int j = base + t; j < end; j += 256)
            atomicAdd(&lcnt[((stg_sp[(size_t)g * NE + j].x >> 15) & 0x7fff) - n0], 1);
    } else {
        for (int j = base + t; j < end; j += 256)
            atomicAdd(&lcnt[((stg_g[j] >> 15) & 0x7fff) - n0], 1);
    }
    __syncthreads();
    int v = lcnt[t];
    __syncthreads();
    for (int d = 1; d < 256; d <<= 1) {
        int u = (t >= d) ? lcnt[t - d] : 0;
        __syncthreads();
        lcnt[t] += u;
        __syncthreads();
    }
    loff[t] = base + lcnt[t] - v;
    if (t == 255) loff[256] = base + lcnt[255];
    __syncthreads();
    if (t < nlen) off6[g * (NN + 1) + n0 + t] = loff[t];
    lcnt[t] = 0;
    __syncthreads();
    if (g < 5) {
        for (int j = base + t; j < end; j += 256) {
            int2 pk = stg_sp[(size_t)g * NE + j];
            int ln = ((pk.x >> 15) & 0x7fff) - n0;
            int p = loff[ln] + atomicAdd(&lcnt[ln], 1);
            int2 o; o.x = pk.x & 0x7fff; o.y = pk.y;
            spp[(size_t)g * NE + p] = o;
        }
    } else {
        for (int j = base + t; j < end; j += 256) {
            int w = stg_g[j];
            int ln = ((w >> 15) & 0x7fff) - n0;
            int p = loff[ln] + atomicAdd(&lcnt[ln], 1);
            g_src[p] = w & 0x7fff;
        }
    }
}

// ---------------- device: gat_agg2 body (phase1 inline + 4-way phase2) ----------------
__device__ __forceinline__ void acc8(float* a, float al, uint4 v) {
    a[0] = fmaf(al, bf2f(v.x & 0xffffu), a[0]); a[1] = fmaf(al, bf2f(v.x >> 16), a[1]);
    a[2] = fmaf(al, bf2f(v.y & 0xffffu), a[2]); a[3] = fmaf(al, bf2f(v.y >> 16), a[3]);
    a[4] = fmaf(al, bf2f(v.z & 0xffffu), a[4]); a[5] = fmaf(al, bf2f(v.z >> 16), a[5]);
    a[6] = fmaf(al, bf2f(v.w & 0xffffu), a[6]); a[7] = fmaf(al, bf2f(v.w >> 16), a[7]);
}

__device__ __forceinline__ void gat_body(int wid, int lane,
                                         const int* __restrict__ goff, const int* __restrict__ gsrc,
                                         const float* __restrict__ as_, const float* __restrict__ ad_,
                                         const unsigned short* __restrict__ xcur,
                                         unsigned short* __restrict__ agg) {
    const int hd = lane >> 4;
    const int cl = (lane & 15) * 8;
    const int s0 = goff[wid], s1 = goff[wid + 1];
    const float4 adv4 = *(const float4*)(ad_ + (size_t)wid * 4);

    float m[4] = {-1e30f, -1e30f, -1e30f, -1e30f};
    float s[4] = {0.f, 0.f, 0.f, 0.f};
    for (int j = s0 + lane; j < s1; j += 64) {
        const int si = gsrc[j];
        float4 av = *(const float4*)(as_ + (size_t)si * 4);
        float e[4] = {lrelu02(av.x + adv4.x), lrelu02(av.y + adv4.y),
                      lrelu02(av.z + adv4.z), lrelu02(av.w + adv4.w)};
        #pragma unroll
        for (int h = 0; h < 4; ++h) {
            if (e[h] > m[h]) { s[h] = s[h] * __expf(m[h] - e[h]) + 1.f; m[h] = e[h]; }
            else             { s[h] += __expf(e[h] - m[h]); }
        }
    }
    #pragma unroll
    for (int d = 1; d < 64; d <<= 1) {
        #pragma unroll
        for (int h = 0; h < 4; ++h) {
            float om = __shfl_xor(m[h], d);
            float os = __shfl_xor(s[h], d);
            float nm = fmaxf(m[h], om);
            s[h] = s[h] * __expf(m[h] - nm) + os * __expf(om - nm);
            m[h] = nm;
        }
    }
    const float advh = hd == 0 ? adv4.x : hd == 1 ? adv4.y : hd == 2 ? adv4.z : adv4.w;
    const float mv   = hd == 0 ? m[0]   : hd == 1 ? m[1]   : hd == 2 ? m[2]   : m[3];
    const float dv   = hd == 0 ? s[0]   : hd == 1 ? s[1]   : hd == 2 ? s[2]   : s[3];
    const float inv  = 1.f / (dv + 1e-16f);

    float ac[8] = {};
    int j = s0;
    for (; j + 3 < s1; j += 4) {
        int i0 = gsrc[j], i1 = gsrc[j + 1], i2 = gsrc[j + 2], i3 = gsrc[j + 3];
        float q0 = as_[(size_t)i0 * 4 + hd], q1 = as_[(size_t)i1 * 4 + hd];
        float q2 = as_[(size_t)i2 * 4 + hd], q3 = as_[(size_t)i3 * 4 + hd];
        uint4 v0 = *(const uint4*)(xcur + (size_t)i0 * 128 + cl);
        uint4 v1 = *(const uint4*)(xcur + (size_t)i1 * 128 + cl);
        uint4 v2 = *(const uint4*)(xcur + (size_t)i2 * 128 + cl);
        uint4 v3 = *(const uint4*)(xcur + (size_t)i3 * 128 + cl);
        float al0 = __expf(lrelu02(q0 + advh) - mv) * inv;
        float al1 = __expf(lrelu02(q1 + advh) - mv) * inv;
        float al2 = __expf(lrelu02(q2 + advh) - mv) * inv;
        float al3 = __expf(lrelu02(q3 + advh) - mv) * inv;
        acc8(ac, al0, v0); acc8(ac, al1, v1); acc8(ac, al2, v2); acc8(ac, al3, v3);
    }
    for (; j < s1; ++j) {
        int si = gsrc[j];
        float q = as_[(size_t)si * 4 + hd];
        uint4 v = *(const uint4*)(xcur + (size_t)si * 128 + cl);
        float al = __expf(lrelu02(q + advh) - mv) * inv;
        acc8(ac, al, v);
    }
    uint4 ov;
    ov.x = (unsigned)f2bf(ac[0]) | ((unsigned)f2bf(ac[1]) << 16);
    ov.y = (unsigned)f2bf(ac[2]) | ((unsigned)f2bf(ac[3]) << 16);
    ov.z = (unsigned)f2bf(ac[4]) | ((unsigned)f2bf(ac[5]) << 16);
    ov.w = (unsigned)f2bf(ac[6]) | ((unsigned)f2bf(ac[7]) << 16);
    *(uint4*)(agg + (size_t)wid * 512 + hd * 128 + cl) = ov;
}

__global__ void __launch_bounds__(256) gat_agg2(const int* __restrict__ goff, const int* __restrict__ gsrc,
                                                const float* __restrict__ as_, const float* __restrict__ ad_,
                                                const unsigned short* __restrict__ xcur,
                                                unsigned short* __restrict__ agg) {
    gat_body(blockIdx.x * 4 + (threadIdx.x >> 6), threadIdx.x & 63, goff, gsrc, as_, ad_, xcur, agg);
}

// ---------------- device: fusedGM body, 40KB-LDS variant (for combined kernel) ----------------
__device__ __forceinline__ void gm40_body(int bm, int t, char* shm,
                                          const unsigned short* __restrict__ agg,
                                          const unsigned short* __restrict__ gatWT,
                                          const unsigned short* __restrict__ mlpWT,
                                          const float* __restrict__ gat_b,
                                          const float* __restrict__ mlp_b,
                                          const float* __restrict__ bng, const float* __restrict__ bnb,
                                          const float* __restrict__ bnm, const float* __restrict__ bnv,
                                          float* __restrict__ x2) {
    char* Ab = shm;                 // 8K  (64 x 64k)
    char* Bb = shm + 8192;          // 16K (128 x 64k)
    char* gt = shm + 8192 + 16384;  // 16K gtile
    const int wave = t >> 6, lane = t & 63;
    const int wr = (wave >> 1) * 32, wc = (wave & 1) * 64;
    const int l15 = lane & 15, l4 = lane >> 4;
    const int rsw = (l15 & 7) << 4;
    f32x4 acc2[2][4] = {};

    #pragma unroll
    for (int h = 0; h < 4; ++h) {
        f32x4 a1[2][4] = {};
        #pragma unroll
        for (int ks2 = 0; ks2 < 2; ++ks2) {
            stage64<64>(agg, 512, bm, NN - 1, h * 128 + ks2 * 64, Ab, t);
            stage64<128>(gatWT, 128, h * 128, 511, ks2 * 64, Bb, t);
            __syncthreads();
            #pragma unroll
            for (int kk = 0; kk < 2; ++kk) {
                bf16x8 af[2], bf[4];
                const int koff = kk * 64 + l4 * 16;
                #pragma unroll
                for (int fm = 0; fm < 2; ++fm)
                    af[fm] = *(const bf16x8*)(Ab + (wr + fm * 16 + l15) * 128 + (koff ^ rsw));
                #pragma unroll
                for (int fn = 0; fn < 4; ++fn)
                    bf[fn] = *(const bf16x8*)(Bb + (wc + fn * 16 + l15) * 128 + (koff ^ rsw));
                #pragma unroll
                for (int fm = 0; fm < 2; ++fm)
                    #pragma unroll
                    for (int fn = 0; fn < 4; ++fn)
                        a1[fm][fn] = __builtin_amdgcn_mfma_f32_16x16x32_bf16(af[fm], bf[fn], a1[fm][fn], 0, 0, 0);
            }
            __syncthreads();
        }
        // ELU + bias -> gtile (chunk ^ (row&7) swizzle)
        #pragma unroll
        for (int fn = 0; fn < 4; ++fn) {
            const int cc = wc + fn * 16 + l15;
            const float gb = gat_b[h * 128 + cc];
            #pragma unroll
            for (int fm = 0; fm < 2; ++fm) {
                #pragma unroll
                for (int rg = 0; rg < 4; ++rg) {
                    const int r = wr + fm * 16 + l4 * 4 + rg;
                    const unsigned short v = f2bf(eluf(a1[fm][fn][rg] + gb));
                    *(unsigned short*)(gt + r * 256 + ((((cc >> 3) ^ (r & 7)) << 4) | ((cc & 7) << 1))) = v;
                }
            }
        }
        #pragma unroll
        for (int ks2 = 0; ks2 < 2; ++ks2) {
            stage64<128>(mlpWT, 512, 0, 127, h * 128 + ks2 * 64, Bb, t);
            __syncthreads();   // orders gtile writes + Bb stage
            #pragma unroll
            for (int kk = 0; kk < 2; ++kk) {
                bf16x8 af[2], bf[4];
                #pragma unroll
                for (int fm = 0; fm < 2; ++fm) {
                    const int r2 = wr + fm * 16 + l15;
                    const int chunk = (ks2 * 8 + kk * 4 + l4) ^ (r2 & 7);
                    af[fm] = *(const bf16x8*)(gt + r2 * 256 + (chunk << 4));
                }
                const int koff = kk * 64 + l4 * 16;
                #pragma unroll
                for (int fn = 0; fn < 4; ++fn)
                    bf[fn] = *(const bf16x8*)(Bb + (wc + fn * 16 + l15) * 128 + (koff ^ rsw));
                #pragma unroll
                for (int fm = 0; fm < 2; ++fm)
                    #pragma unroll
                    for (int fn = 0; fn < 4; ++fn)
                        acc2[fm][fn] = __builtin_amdgcn_mfma_f32_16x16x32_bf16(af[fm], bf[fn], acc2[fm][fn], 0, 0, 0);
            }
            __syncthreads();
        }
    }

    #pragma unroll
    for (int fn = 0; fn < 4; ++fn) {
        const int c = wc + fn * 16 + l15;
        const float sc = bng[c] * rsqrtf(bnv[c] + BN_EPS);
        const float sh = bnb[c] - bnm[c] * sc;
        const float mb = mlp_b[c];
        #pragma unroll
        for (int fm = 0; fm < 2; ++fm) {
            #pragma unroll
            for (int rg = 0; rg < 4; ++rg) {
                int r = bm + wr + fm * 16 + l4 * 4 + rg;
                if (r < NN)
                    x2[(size_t)r * 128 + c] += (acc2[fm][fn][rg] + mb) * sc + sh;
            }
        }
    }
}

// standalone fusedGM (40K variant; used for last set)
__global__ void __launch_bounds__(256) fusedGM(const unsigned short* __restrict__ agg,
                                               const unsigned short* __restrict__ gatWT,
                                               const unsigned short* __restrict__ mlpWT,
                                               const float* __restrict__ gat_b,
                                               const float* __restrict__ mlp_b,
                                               const float* __restrict__ bng, const float* __restrict__ bnb,
                                               const float* __restrict__ bnm, const float* __restrict__ bnv,
                                               float* __restrict__ x2) {
    __shared__ __align__(16) char shm[40960];
    gm40_body(blockIdx.x * 64, threadIdx.x, shm, agg, gatWT, mlpWT, gat_b, mlp_b,
              bng, bnb, bnm, bnv, x2);
}

// ---------------- comb: gat_agg2(set i+1) || fusedGM(set i), interleaved blocks ----------------
__global__ void __launch_bounds__(256) comb(const int* __restrict__ goff, const int* __restrict__ gsrc,
                                            const float* __restrict__ as_g, const float* __restrict__ ad_g,
                                            const unsigned short* __restrict__ xcur_g,
                                            unsigned short* __restrict__ agg_w,
                                            const unsigned short* __restrict__ agg_r,
                                            const unsigned short* __restrict__ gatWT,
                                            const unsigned short* __restrict__ mlpWT,
                                            const float* __restrict__ gat_b,
                                            const float* __restrict__ mlp_b,
                                            const float* __restrict__ bng, const float* __restrict__ bnb,
                                            const float* __restrict__ bnm, const float* __restrict__ bnv,
                                            float* __restrict__ x2) {
    __shared__ __align__(16) char shm[40960];
    const int bid = blockIdx.x;
    const int g17 = bid / 17, r17 = bid % 17;
    if (r17 == 0) {
        // GM block (469 total)
        gm40_body(g17 * 64, threadIdx.x, shm, agg_r, gatWT, mlpWT, gat_b, mlp_b,
                  bng, bnb, bnm, bnv, x2);
    } else {
        const int gatId = g17 * 16 + (r17 - 1);
        if (gatId >= 7500) return;
        gat_body(gatId * 4 + (threadIdx.x >> 6), threadIdx.x & 63,
                 goff, gsrc, as_g, ad_g, xcur_g, agg_w);
    }
}

// ---------------- sp_abs4 ----------------
__global__ void __launch_bounds__(256) sp_abs4(const int* __restrict__ off6,
                                               const int2* __restrict__ spp,
                                               const unsigned short* __restrict__ hb,
                                               unsigned short* __restrict__ tmp4) {
    const int y = blockIdx.y;
    const int* off = off6 + (y + 1) * (NN + 1);
    const int2* pk = spp + (size_t)(y + 1) * NE;
    unsigned short* out = tmp4 + (size_t)y * NN * 128;

    const int wid  = blockIdx.x * 4 + (threadIdx.x >> 6);
    const int lane = threadIdx.x & 63;
    const int co   = lane * 2;
    const int s0 = off[wid], s1 = off[wid + 1];
    float a0 = 0.f, a1 = 0.f;
    int j = s0;
    for (; j + 7 < s1; j += 8) {
        int2 e[8];
        unsigned v[8];
        #pragma unroll
        for (int q = 0; q < 8; ++q) e[q] = pk[j + q];
        #pragma unroll
        for (int q = 0; q < 8; ++q) v[q] = *(const unsigned*)(hb + (size_t)e[q].x * 128 + co);
        #pragma unroll
        for (int q = 0; q < 8; ++q) {
            float w = __int_as_float(e[q].y);
            a0 = fmaf(w, bf2f(v[q] & 0xffffu), a0);
            a1 = fmaf(w, bf2f(v[q] >> 16), a1);
        }
    }
    for (; j < s1; ++j) {
        int2 e = pk[j];
        float wj = __int_as_float(e.y);
        unsigned v = *(const unsigned*)(hb + (size_t)e.x * 128 + co);
        a0 = fmaf(wj, bf2f(v & 0xffffu), a0);
        a1 = fmaf(wj, bf2f(v >> 16), a1);
    }
    a0 = fabsf(a0); a1 = fabsf(a1);
    unsigned o = (unsigned)f2bf(a0) | ((unsigned)f2bf(a1) << 16);
    *(unsigned*)(out + (size_t)wid * 128 + co) = o;
}

// ---------------- sp_fused5 (tbl[5], 4-way) ----------------
__global__ void __launch_bounds__(256) sp_fused5(const int* __restrict__ off0,
                                                 const int2* __restrict__ spp0,
                                                 const unsigned short* __restrict__ hb,
                                                 const unsigned short* __restrict__ tmp4,
                                                 unsigned short* __restrict__ xcur5,
                                                 const float* __restrict__ watt,
                                                 float* __restrict__ as5,
                                                 float* __restrict__ ad5) {
    __shared__ float sWatt[5120];
    for (int i = threadIdx.x; i < 5120; i += 256) sWatt[i] = watt[i];
    __syncthreads();

    const int wid  = blockIdx.x * 4 + (threadIdx.x >> 6);
    const int lane = threadIdx.x & 63;
    const int co   = lane * 2;
    const int s0 = off0[wid], s1 = off0[wid + 1];
    const unsigned short* tbl[5] = {
        hb, tmp4, tmp4 + (size_t)1 * NN * 128, tmp4 + (size_t)2 * NN * 128, tmp4 + (size_t)3 * NN * 128 };

    float a[5][2] = {};
    int j = s0;
    for (; j + 3 < s1; j += 4) {
        int2 e0 = spp0[j], e1 = spp0[j + 1], e2 = spp0[j + 2], e3 = spp0[j + 3];
        size_t r0 = (size_t)e0.x * 128 + co, r1 = (size_t)e1.x * 128 + co;
        size_t r2 = (size_t)e2.x * 128 + co, r3 = (size_t)e3.x * 128 + co;
        unsigned v[5][4];
        #pragma unroll
        for (int y = 0; y < 5; ++y) {
            v[y][0] = *(const unsigned*)(tbl[y] + r0);
            v[y][1] = *(const unsigned*)(tbl[y] + r1);
            v[y][2] = *(const unsigned*)(tbl[y] + r2);
            v[y][3] = *(const unsigned*)(tbl[y] + r3);
        }
        float w0 = __int_as_float(e0.y), w1 = __int_as_float(e1.y);
        float w2 = __int_as_float(e2.y), w3 = __int_as_float(e3.y);
        #pragma unroll
        for (int y = 0; y < 5; ++y) {
            a[y][0] = fmaf(w0, bf2f(v[y][0] & 0xffffu), a[y][0]); a[y][1] = fmaf(w0, bf2f(v[y][0] >> 16), a[y][1]);
            a[y][0] = fmaf(w1, bf2f(v[y][1] & 0xffffu), a[y][0]); a[y][1] = fmaf(w1, bf2f(v[y][1] >> 16), a[y][1]);
            a[y][0] = fmaf(w2, bf2f(v[y][2] & 0xffffu), a[y][0]); a[y][1] = fmaf(w2, bf2f(v[y][2] >> 16), a[y][1]);
            a[y][0] = fmaf(w3, bf2f(v[y][3] & 0xffffu), a[y][0]); a[y][1] = fmaf(w3, bf2f(v[y][3] >> 16), a[y][1]);
        }
    }
    for (; j < s1; ++j) {
        int2 e = spp0[j];
        size_t r = (size_t)e.x * 128 + co;
        float wj = __int_as_float(e.y);
        #pragma unroll
        for (int y = 0; y < 5; ++y) {
            unsigned v = *(const unsigned*)(tbl[y] + r);
            a[y][0] = fmaf(wj, bf2f(v & 0xffffu), a[y][0]);
            a[y][1] = fmaf(wj, bf2f(v >> 16), a[y][1]);
        }
    }
    #pragma unroll
    for (int y = 0; y < 5; ++y) {
        unsigned o = (unsigned)f2bf(a[y][0]) | ((unsigned)f2bf(a[y][1]) << 16);
        *(unsigned*)(xcur5 + (size_t)y * NN * 128 + (size_t)wid * 128 + co) = o;
    }

    #pragma unroll
    for (int i = 0; i < 5; ++i) {
        #pragma unroll
        for (int h = 0; h < 4; ++h) {
            const float* wS = sWatt + ((i * 2 + 0) * 4 + h) * 128;
            const float* wD = sWatt + ((i * 2 + 1) * 4 + h) * 128;
            float ps = a[i][0] * wS[co] + a[i][1] * wS[co + 1];
            float pd = a[i][0] * wD[co] + a[i][1] * wD[co + 1];
            #pragma unroll
            for (int dd = 1; dd < 64; dd <<= 1) { ps += __shfl_xor(ps, dd); pd += __shfl_xor(pd, dd); }
            if (lane == 0) {
                as5[(size_t)i * NN * 4 + (size_t)wid * 4 + h] = ps;
                ad5[(size_t)i * NN * 4 + (size_t)wid * 4 + h] = pd;
            }
        }
    }
}

// ---------------- final ----------------
__global__ void __launch_bounds__(256) final_out(const float* __restrict__ x2,
                                                 const float* __restrict__ bn0g, const float* __restrict__ bn0b,
                                                 const float* __restrict__ bn0m, const float* __restrict__ bn0v,
                                                 const float* __restrict__ outW, const float* __restrict__ outb,
                                                 float* __restrict__ out) {
    __shared__ float sW[128 * 12];
    __shared__ float sSc[128], sSh[128];
    for (int i = threadIdx.x; i < 1280; i += 256) {
        int r = i / 10, c = i - r * 10;
        sW[r * 12 + c] = outW[i];
    }
    if (threadIdx.x < 128) {
        int c = threadIdx.x;
        float sc = bn0g[c] * rsqrtf(bn0v[c] + BN_EPS);
        sSc[c] = sc;
        sSh[c] = bn0b[c] - bn0m[c] * sc;
    }
    __syncthreads();
    const int wid  = blockIdx.x * 4 + (threadIdx.x >> 6);
    const int lane = threadIdx.x & 63;
    const int c0 = lane * 2;
    float2 a = *(const float2*)(x2 + (size_t)wid * 128 + c0);
    float a0 = eluf(a.x * sSc[c0] + sSh[c0]);
    float a1 = eluf(a.y * sSc[c0 + 1] + sSh[c0 + 1]);
    float p[NCLS];
    #pragma unroll
    for (int j = 0; j < NCLS; ++j)
        p[j] = a0 * sW[c0 * 12 + j] + a1 * sW[(c0 + 1) * 12 + j];
    #pragma unroll
    for (int j = 0; j < NCLS; ++j) {
        float v = p[j];
        v += __shfl_xor(v, 1);  v += __shfl_xor(v, 2);  v += __shfl_xor(v, 4);
        v += __shfl_xor(v, 8);  v += __shfl_xor(v, 16); v += __shfl_xor(v, 32);
        p[j] = v;
    }
    float z[NCLS];
    #pragma unroll
    for (int j = 0; j < NCLS; ++j) z[j] = p[j] + outb[j];
    float m = z[0];
    #pragma unroll
    for (int j = 1; j < NCLS; ++j) m = fmaxf(m, z[j]);
    float ssum = 0.f;
    #pragma unroll
    for (int j = 0; j < NCLS; ++j) ssum += __expf(z[j] - m);
    float lse = m + __logf(ssum);
    #pragma unroll
    for (int j = 0; j < NCLS; ++j)
        if (lane == j) out[(size_t)wid * NCLS + j] = z[j] - lse;
}

// ---------------- launcher ----------------
extern "C" void kernel_launch(void* const* d_in, const int* in_sizes, int n_in,
                              void* d_out, int out_size, void* d_ws, size_t ws_size,
                              hipStream_t stream) {
    const float* x        = (const float*)d_in[0];
    const int*   edge_ix  = (const int*)  d_in[1];
    const int*   scat_idx = (const int*)  d_in[2];
    const float* scat_w   = (const float*)d_in[3];
    const float* lin_W    = (const float*)d_in[4];
    const float* lin_b    = (const float*)d_in[5];
    const float* gat_W    = (const float*)d_in[6];
    const float* att_src  = (const float*)d_in[7];
    const float* att_dst  = (const float*)d_in[8];
    const float* gat_b    = (const float*)d_in[9];
    const float* mlp_W    = (const float*)d_in[10];
    const float* mlp_b    = (const float*)d_in[11];
    const float* bn_g     = (const float*)d_in[12];
    const float* bn_b     = (const float*)d_in[13];
    const float* bn_m     = (const float*)d_in[14];
    const float* bn_v     = (const float*)d_in[15];
    const float* bn0_g    = (const float*)d_in[16];
    const float* bn0_b    = (const float*)d_in[17];
    const float* bn0_m    = (const float*)d_in[18];
    const float* bn0_v    = (const float*)d_in[19];
    const float* out_W    = (const float*)d_in[20];
    const float* out_b    = (const float*)d_in[21];
    float* out = (float*)d_out;

    char* ws = (char*)d_ws;
    unsigned short* xb    = (unsigned short*)(ws + OFF_U1);
    unsigned short* xcur5 = (unsigned short*)(ws + OFF_U1);
    unsigned short* hb    = (unsigned short*)(ws + OFF_HB);
    float*          x2    = (float*)(ws + OFF_X2);
    unsigned short* aggA  = (unsigned short*)(ws + OFF_AGG);
    unsigned short* tmp4  = (unsigned short*)(ws + OFF_GOUT);
    unsigned short* aggB  = (unsigned short*)(ws + OFF_GOUT);  // tmp4 dead after sp_fused5
    int2*  stg_sp = (int2*)(ws + OFF_GOUT);
    int*   stg_g  = (int*)(ws + OFF_GOUT + (size_t)NSETS * NE * 8);
    unsigned short* wt    = (unsigned short*)(ws + OFF_WT);
    unsigned short* linWT = wt;
    unsigned short* gatWT = wt + 65536;
    unsigned short* mlpWT = wt + 65536 * 6;
    float* watt   = (float*)(ws + OFF_WATT);
    int*   off6   = (int*)(ws + OFF_OFF6);
    int2*  spp    = (int2*)(ws + OFF_SPP);
    int*   g_src  = (int*)(ws + OFF_GSRC);
    int*   bh     = (int*)(ws + OFF_CNT);
    int*   bb     = bh + NBLK_SORT * NWGMAX;
    float* as5    = (float*)(ws + OFF_AS5);
    float* ad5    = (float*)(ws + OFF_AD5);

    const dim3 b256(256);
    const int* goff = off6 + 5 * (NN + 1);

    // ---- CSR build + dtype prep ----
    prep1<<<PREP_GRID, b256, 0, stream>>>(scat_idx, edge_ix, bh, x, xb,
                                          lin_W, gat_W, mlp_W, linWT, gatWT, mlpWT,
                                          att_src, att_dst, watt);
    bktscan<<<6, 128, 0, stream>>>(bh, bb, off6);
    wgscan<<<NBLK_SORT, 128, 0, stream>>>(bb, bh);
    binlin<<<LIN_B + NBLK_BIN, b256, 0, stream>>>(scat_idx, scat_w, edge_ix, bh, stg_sp, stg_g,
                                                  xb, linWT, lin_b, hb, x2);
    sortP<<<NBLK_SORT, b256, 0, stream>>>(bb, stg_sp, stg_g, spp, g_src, off6);

    // ---- solo passes (+ fused attention scores) ----
    sp_abs4<<<dim3(7500, 4), b256, 0, stream>>>(off6, spp, hb, tmp4);
    sp_fused5<<<7500, b256, 0, stream>>>(off6, spp, hb, tmp4, xcur5, watt, as5, ad5);

    // ---- pipelined GAT branches: agg2(i+1) || fusedGM(i) ----
    unsigned short* aggbuf[2] = { aggA, aggB };
    // set 0 aggregation alone (full occupancy)
    gat_agg2<<<7500, b256, 0, stream>>>(goff, g_src, as5, ad5, xcur5, aggA);
    for (int i = 1; i < NSETS; ++i) {
        comb<<<COMB_GRID, b256, 0, stream>>>(
            goff, g_src,
            as5 + (size_t)i * NN * 4, ad5 + (size_t)i * NN * 4,
            xcur5 + (size_t)i * NN * 128, aggbuf[i & 1],           // gat writes set i
            aggbuf[(i - 1) & 1],                                    // GM reads set i-1
            gatWT + (size_t)(i - 1) * 65536, mlpWT + (size_t)(i - 1) * 65536,
            gat_b + (size_t)(i - 1) * 512, mlp_b + (size_t)(i - 1) * 128,
            bn_g + (size_t)(i - 1) * 128, bn_b + (size_t)(i - 1) * 128,
            bn_m + (size_t)(i - 1) * 128, bn_v + (size_t)(i - 1) * 128, x2);
    }
    // last set GEMM alone
    fusedGM<<<GM_B, b256, 0, stream>>>(aggbuf[4 & 1], gatWT + (size_t)4 * 65536, mlpWT + (size_t)4 * 65536,
                                       gat_b + (size_t)4 * 512, mlp_b + (size_t)4 * 128,
                                       bn_g + (size_t)4 * 128, bn_b + (size_t)4 * 128,
                                       bn_m + (size_t)4 * 128, bn_v + (size_t)4 * 128, x2);

    // ---- final ----
    final_out<<<7500, b256, 0, stream>>>(x2, bn0_g, bn0_b, bn0_m, bn0_v, out_W, out_b, out);
}

// Round 15
// 592.159 us; speedup vs baseline: 1.5815x; 1.5815x over previous
//
#include <hip/hip_runtime.h>
#include <cstdint>
#include <cstddef>

// ---------------- problem constants ----------------
#define NN 30000        // nodes
#define NE 400000       // edges per scatter set
#define EG (NE + NN)    // GAT edges incl self loops
#define NSETS 5
#define NCLS 10
#define BN_EPS 1e-5f

// bucketed CSR build
#define NBKT 118
#define CHUNK 4096
#define NWG_SET 98
#define NWG_GAT 105
#define NWGMAX 105
#define NBLK_BIN (5 * NWG_SET + NWG_GAT)   // 595
#define NBLK_SORT (6 * NBKT)               // 708
#define LIN_B 469

typedef __bf16 bf16x8 __attribute__((ext_vector_type(8)));
typedef float  f32x4  __attribute__((ext_vector_type(4)));

// ---------------- workspace layout (bytes) ----------------
constexpr size_t alg(size_t x) { return (x + 255) & ~size_t(255); }
constexpr size_t OFF_U1    = 0;                                        // xb | xcur5
constexpr size_t OFF_HB    = OFF_U1   + alg((size_t)5 * NN * 128 * 2);
constexpr size_t OFF_X2    = OFF_HB   + alg((size_t)NN * 128 * 2);
constexpr size_t OFF_AGG   = OFF_X2   + alg((size_t)NN * 128 * 4);
constexpr size_t OFF_GOUT  = OFF_AGG  + alg((size_t)NN * 512 * 2);     // CSR staging -> tmp4
constexpr size_t OFF_WT    = OFF_GOUT + alg((size_t)NN * 512 * 2);
constexpr size_t OFF_WATT  = OFF_WT   + alg((size_t)11 * 65536 * 2);
constexpr size_t OFF_OFF6  = OFF_WATT + alg((size_t)5 * 2 * 4 * 128 * 4);
constexpr size_t OFF_SPP   = OFF_OFF6 + alg((size_t)6 * (NN + 1) * 4);
constexpr size_t OFF_GSRC  = OFF_SPP  + alg((size_t)NSETS * NE * 8);
constexpr size_t OFF_CNT   = OFF_GSRC + alg((size_t)EG * 4);
constexpr size_t OFF_AS5   = OFF_CNT  + alg((size_t)12 * NN * 4);
constexpr size_t OFF_AD5   = OFF_AS5  + alg((size_t)5 * NN * 4 * 4);
constexpr size_t WS_NEED   = OFF_AD5  + alg((size_t)5 * NN * 4 * 4);   // ~149 MB

// ---------------- helpers ----------------
__device__ __forceinline__ float lrelu02(float v) { return v > 0.f ? v : 0.2f * v; }
__device__ __forceinline__ float eluf(float v)    { return v > 0.f ? v : __expf(v) - 1.f; }
__device__ __forceinline__ float bf2f(unsigned u) {
    union { unsigned i; float f; } c; c.i = u << 16; return c.f;
}
__device__ __forceinline__ unsigned short f2bf(float f) {
    union { float f; unsigned i; } c; c.f = f;
    unsigned u = c.i + 0x7FFFu + ((c.i >> 16) & 1u);
    return (unsigned short)(u >> 16);
}
__device__ __forceinline__ void gload_lds16(const void* g, void* l) {
    __builtin_amdgcn_global_load_lds(
        (const __attribute__((address_space(1))) void*)(uintptr_t)g,
        (__attribute__((address_space(3))) void*)(unsigned)(uintptr_t)l,
        16, 0, 0);
}

__device__ __forceinline__ void chunk_map(int blk, int& g, int& wg, int& e0, int& e1) {
    if (blk < 5 * NWG_SET) { g = blk / NWG_SET; wg = blk - g * NWG_SET; }
    else                   { g = 5;             wg = blk - 5 * NWG_SET; }
    e0 = wg * CHUNK;
    e1 = min(e0 + CHUNK, (g < 5) ? NE : EG);
}

// ---------------- prep1: hist | convx | transW | wattk ----------------
#define PREP_CVX_B 1024
#define PREP_TRW_B 512
#define PREP_WAT_B 20
#define PREP_HIST_B NBLK_BIN
#define PREP_GRID (PREP_CVX_B + PREP_TRW_B + PREP_WAT_B + PREP_HIST_B)

__global__ void prep1(const int* __restrict__ scat_idx, const int* __restrict__ edge_ix,
                      int* __restrict__ bh,
                      const float* __restrict__ x, unsigned short* __restrict__ xb,
                      const float* __restrict__ lin_W, const float* __restrict__ gat_W,
                      const float* __restrict__ mlp_W,
                      unsigned short* __restrict__ linWT, unsigned short* __restrict__ gatWT,
                      unsigned short* __restrict__ mlpWT,
                      const float* __restrict__ att_src, const float* __restrict__ att_dst,
                      float* __restrict__ watt) {
    __shared__ int h[NBKT];
    const int b = blockIdx.x;
    if (b < PREP_CVX_B) {
        const int total = NN * 512 / 4;
        for (int i = b * 256 + threadIdx.x; i < total; i += PREP_CVX_B * 256) {
            float4 v = *(const float4*)(x + (size_t)i * 4);
            ushort4 o;
            o.x = f2bf(v.x); o.y = f2bf(v.y); o.z = f2bf(v.z); o.w = f2bf(v.w);
            *(ushort4*)(xb + (size_t)i * 4) = o;
        }
    } else if (b < PREP_CVX_B + PREP_TRW_B) {
        const int bb = b - PREP_CVX_B;
        const int total = 65536 + 2 * 327680;
        for (int i = bb * 256 + threadIdx.x; i < total; i += PREP_TRW_B * 256) {
            if (i < 65536) {
                int n = i >> 9, k = i & 511;
                linWT[i] = f2bf(lin_W[(size_t)k * 128 + n]);
            } else if (i < 65536 + 327680) {
                int li = i - 65536;
                int st = li >> 16, r = li & 65535;
                int n = r >> 7, k = r & 127;
                gatWT[li] = f2bf(gat_W[(size_t)st * 65536 + (size_t)k * 512 + n]);
            } else {
                int li = i - 65536 - 327680;
                int st = li >> 16, r = li & 65535;
                int n = r >> 9, k = r & 511;
                mlpWT[li] = f2bf(mlp_W[(size_t)st * 65536 + (size_t)k * 128 + n]);
            }
        }
    } else if (b < PREP_CVX_B + PREP_TRW_B + PREP_WAT_B) {
        const int tid = (b - PREP_CVX_B - PREP_TRW_B) * 256 + threadIdx.x;
        if (tid < 5120) {
            int k = tid & 127, hh = (tid >> 7) & 3, tt = (tid >> 9) & 1, i = tid >> 10;
            const float* att = (tt == 0 ? att_src : att_dst) + ((size_t)i * 4 + hh) * 128;
            const float* Wr  = gat_W + ((size_t)i * 128 + k) * 512 + hh * 128;
            float s = 0.f;
            #pragma unroll 8
            for (int c = 0; c < 128; ++c) s = fmaf(Wr[c], att[c], s);
            watt[tid] = s;
        }
    } else {
        const int blk = b - (PREP_CVX_B + PREP_TRW_B + PREP_WAT_B);
        int g, wg, e0, e1;
        chunk_map(blk, g, wg, e0, e1);
        for (int i = threadIdx.x; i < NBKT; i += 256) h[i] = 0;
        __syncthreads();
        if (g < 5) {
            const int* dsts = scat_idx + (size_t)g * 2 * NE + NE;
            for (int e = e0 + threadIdx.x; e < e1; e += 256)
                atomicAdd(&h[dsts[e] >> 8], 1);
        } else {
            for (int e = e0 + threadIdx.x; e < e1; e += 256) {
                int d = (e < NE) ? edge_ix[NE + e] : (e - NE);
                atomicAdd(&h[d >> 8], 1);
            }
        }
        __syncthreads();
        for (int i = threadIdx.x; i < NBKT; i += 256)
            bh[(size_t)(g * NBKT + i) * NWGMAX + wg] = h[i];
    }
}

// ---------------- bktscan ----------------
__global__ void bktscan(const int* __restrict__ bh, int* __restrict__ bb, int* __restrict__ off6) {
    const int g = blockIdx.x;
    const int t = threadIdx.x;
    const int nwg = (g < 5) ? NWG_SET : NWG_GAT;
    __shared__ int s[128];
    int tot = 0;
    if (t < NBKT) {
        const int* p = bh + (size_t)(g * NBKT + t) * NWGMAX;
        for (int w = 0; w < nwg; ++w) tot += p[w];
    }
    s[t] = tot;
    __syncthreads();
    for (int d = 1; d < 128; d <<= 1) {
        int u = (t >= d) ? s[t - d] : 0;
        __syncthreads();
        s[t] += u;
        __syncthreads();
    }
    if (t < NBKT) bb[g * 132 + t] = s[t] - tot;
    if (t == NBKT - 1) {
        bb[g * 132 + NBKT] = s[t];
        off6[g * (NN + 1) + NN] = s[t];
    }
}

// ---------------- wgscan ----------------
__global__ void wgscan(const int* __restrict__ bb, int* __restrict__ bh) {
    const int gb = blockIdx.x;
    const int g = gb / NBKT, bk = gb - g * NBKT;
    __shared__ int s[128];
    const int t = threadIdx.x;
    const int nwg = (g < 5) ? NWG_SET : NWG_GAT;
    int v = (t < nwg) ? bh[(size_t)gb * NWGMAX + t] : 0;
    s[t] = v;
    __syncthreads();
    for (int d = 1; d < 128; d <<= 1) {
        int u = (t >= d) ? s[t - d] : 0;
        __syncthreads();
        s[t] += u;
        __syncthreads();
    }
    const int base = bb[g * 132 + bk];
    if (t < nwg) bh[(size_t)gb * NWGMAX + t] = base + (s[t] - v);
}

// ---------------- staging helper ----------------
template<int ROWS>
__device__ __forceinline__ void stage64(const unsigned short* __restrict__ src, int ld,
                                        int row0, int maxrow, int k0, char* lds, int t) {
    const int wave = t >> 6, lane = t & 63;
    const int sub = lane >> 3;
    const int kch = (lane & 7) ^ sub;
    for (int j = wave; j < ROWS / 8; j += 4) {
        int grow = row0 + j * 8 + sub;
        if (grow > maxrow) grow = maxrow;
        gload_lds16(src + (size_t)grow * ld + k0 + kch * 8, lds + j * 1024);
    }
}

// ---------------- binlin: binP | mgemm_lin ----------------
__global__ void __launch_bounds__(256) binlin(const int* __restrict__ scat_idx, const float* __restrict__ scat_w,
                                              const int* __restrict__ edge_ix, const int* __restrict__ pos,
                                              int2* __restrict__ stg_sp, int* __restrict__ stg_g,
                                              const unsigned short* __restrict__ A,
                                              const unsigned short* __restrict__ BT,
                                              const float* __restrict__ bias,
                                              unsigned short* __restrict__ outb,
                                              float* __restrict__ x2) {
    __shared__ __align__(16) char shm[25600];
    const int t = threadIdx.x;
    if (blockIdx.x < LIN_B) {
        constexpr int K = 512, NC = 128;
        char* As = shm;
        char* Bs = shm + 8192;
        const int wave = t >> 6, lane = t & 63;
        const int bm = blockIdx.x * 64;
        const int wr = (wave >> 1) * 32, wc = (wave & 1) * 64;
        const int l15 = lane & 15, l4 = lane >> 4;
        const int rsw = (l15 & 7) << 4;
        f32x4 acc[2][4] = {};
        for (int kt = 0; kt < K; kt += 64) {
            stage64<64>(A, K, bm, NN - 1, kt, As, t);
            stage64<128>(BT, K, 0, NC - 1, kt, Bs, t);
            __syncthreads();
            #pragma unroll
            for (int kk = 0; kk < 2; ++kk) {
                bf16x8 af[2], bf[4];
                const int koff = kk * 64 + l4 * 16;
                #pragma unroll
                for (int fm = 0; fm < 2; ++fm)
                    af[fm] = *(const bf16x8*)(As + (wr + fm * 16 + l15) * 128 + (koff ^ rsw));
                #pragma unroll
                for (int fn = 0; fn < 4; ++fn)
                    bf[fn] = *(const bf16x8*)(Bs + (wc + fn * 16 + l15) * 128 + (koff ^ rsw));
                #pragma unroll
                for (int fm = 0; fm < 2; ++fm)
                    #pragma unroll
                    for (int fn = 0; fn < 4; ++fn)
                        acc[fm][fn] = __builtin_amdgcn_mfma_f32_16x16x32_bf16(af[fm], bf[fn], acc[fm][fn], 0, 0, 0);
            }
            __syncthreads();
        }
        #pragma unroll
        for (int fn = 0; fn < 4; ++fn) {
            const int c = wc + fn * 16 + l15;
            const float bias_c = bias[c];
            #pragma unroll
            for (int fm = 0; fm < 2; ++fm) {
                #pragma unroll
                for (int rg = 0; rg < 4; ++rg) {
                    int r = bm + wr + fm * 16 + l4 * 4 + rg;
                    if (r < NN) {
                        float v = acc[fm][fn][rg] + bias_c;
                        outb[(size_t)r * NC + c] = f2bf(v);
                        x2[(size_t)r * NC + c] = v;
                    }
                }
            }
        }
    } else {
        int* lpos = (int*)shm;
        int* lcur = lpos + NBKT;
        int g, wg, e0, e1;
        chunk_map(blockIdx.x - LIN_B, g, wg, e0, e1);
        for (int i = t; i < NBKT; i += 256) {
            lpos[i] = pos[(size_t)(g * NBKT + i) * NWGMAX + wg];
            lcur[i] = 0;
        }
        __syncthreads();
        if (g < 5) {
            const int* si = scat_idx + (size_t)g * 2 * NE;
            const float* sw = scat_w + (size_t)g * NE;
            for (int e = e0 + t; e < e1; e += 256) {
                int src = si[e], d = si[NE + e];
                int r = atomicAdd(&lcur[d >> 8], 1);
                int2 pk; pk.x = src | (d << 15); pk.y = __float_as_int(sw[e]);
                stg_sp[(size_t)g * NE + lpos[d >> 8] + r] = pk;
            }
        } else {
            for (int e = e0 + t; e < e1; e += 256) {
                int src, d;
                if (e < NE) { src = edge_ix[e]; d = edge_ix[NE + e]; }
                else        { src = e - NE;     d = src; }
                int r = atomicAdd(&lcur[d >> 8], 1);
                stg_g[lpos[d >> 8] + r] = src | (d << 15);
            }
        }
    }
}

// ---------------- sortP ----------------
__global__ void __launch_bounds__(256) sortP(const int* __restrict__ bb,
                                             const int2* __restrict__ stg_sp, const int* __restrict__ stg_g,
                                             int2* __restrict__ spp, int* __restrict__ g_src,
                                             int* __restrict__ off6) {
    __shared__ int lcnt[256];
    __shared__ int loff[257];
    const int gb = blockIdx.x;
    const int g = gb / NBKT, bk = gb - g * NBKT;
    const int n0 = bk << 8;
    const int nlen = min(256, NN - n0);
    const int base = bb[g * 132 + bk];
    const int end  = bb[g * 132 + bk + 1];
    const int t = threadIdx.x;
    lcnt[t] = 0;
    __syncthreads();
    if (g < 5) {
        for (int j = base + t; j < end; j += 256)
            atomicAdd(&lcnt[((stg_sp[(size_t)g * NE + j].x >> 15) & 0x7fff) - n0], 1);
    } else {
        for (int j = base + t; j < end; j += 256)
            atomicAdd(&lcnt[((stg_g[j] >> 15) & 0x7fff) - n0], 1);
    }
    __syncthreads();
    int v = lcnt[t];
    __syncthreads();
    for (int d = 1; d < 256; d <<= 1) {
        int u = (t >= d) ? lcnt[t - d] : 0;
        __syncthreads();
        lcnt[t] += u;
        __syncthreads();
    }
    loff[t] = base + lcnt[t] - v;
    if (t == 255) loff[256] = base + lcnt[255];
    __syncthreads();
    if (t < nlen) off6[g * (NN + 1) + n0 + t] = loff[t];
    lcnt[t] = 0;
    __syncthreads();
    if (g < 5) {
        for (int j = base + t; j < end; j += 256) {
            int2 pk = stg_sp[(size_t)g * NE + j];
            int ln = ((pk.x >> 15) & 0x7fff) - n0;
            int p = loff[ln] + atomicAdd(&lcnt[ln], 1);
            int2 o; o.x = pk.x & 0x7fff; o.y = pk.y;
            spp[(size_t)g * NE + p] = o;
        }
    } else {
        for (int j = base + t; j < end; j += 256) {
            int w = stg_g[j];
            int ln = ((w >> 15) & 0x7fff) - n0;
            int p = loff[ln] + atomicAdd(&lcnt[ln], 1);
            g_src[p] = w & 0x7fff;
        }
    }
}

// ---------------- fused GATELU + MLP + BN-accumulate (round-13 64KB version) ----------------
__global__ void __launch_bounds__(256) fusedGM(const unsigned short* __restrict__ agg,
                                               const unsigned short* __restrict__ gatWT,
                                               const unsigned short* __restrict__ mlpWT,
                                               const float* __restrict__ gat_b,
                                               const float* __restrict__ mlp_b,
                                               const float* __restrict__ bng, const float* __restrict__ bnb,
                                               const float* __restrict__ bnm, const float* __restrict__ bnv,
                                               float* __restrict__ x2) {
    __shared__ __align__(16) char U[49152];
    __shared__ __align__(16) char gtile[16384];
    const int t = threadIdx.x, wave = t >> 6, lane = t & 63;
    const int bm = blockIdx.x * 64;
    const int wr = (wave >> 1) * 32, wc = (wave & 1) * 64;
    const int l15 = lane & 15, l4 = lane >> 4;
    const int rsw = (l15 & 7) << 4;
    f32x4 acc2[2][4] = {};

    #pragma unroll
    for (int h = 0; h < 4; ++h) {
        stage64<64>(agg, 512, bm, NN - 1, h * 128,       U,         t);
        stage64<64>(agg, 512, bm, NN - 1, h * 128 + 64,  U + 8192,  t);
        stage64<128>(gatWT, 128, h * 128, 511, 0,        U + 16384, t);
        stage64<128>(gatWT, 128, h * 128, 511, 64,       U + 32768, t);
        __syncthreads();

        f32x4 a1[2][4] = {};
        #pragma unroll
        for (int ks = 0; ks < 4; ++ks) {
            const char* Asb = U + (ks >> 1) * 8192;
            const char* Bsb = U + 16384 + (ks >> 1) * 16384;
            const int koff = (ks & 1) * 64 + l4 * 16;
            bf16x8 af[2], bf[4];
            #pragma unroll
            for (int fm = 0; fm < 2; ++fm)
                af[fm] = *(const bf16x8*)(Asb + (wr + fm * 16 + l15) * 128 + (koff ^ rsw));
            #pragma unroll
            for (int fn = 0; fn < 4; ++fn)
                bf[fn] = *(const bf16x8*)(Bsb + (wc + fn * 16 + l15) * 128 + (koff ^ rsw));
            #pragma unroll
            for (int fm = 0; fm < 2; ++fm)
                #pragma unroll
                for (int fn = 0; fn < 4; ++fn)
                    a1[fm][fn] = __builtin_amdgcn_mfma_f32_16x16x32_bf16(af[fm], bf[fn], a1[fm][fn], 0, 0, 0);
        }
        __syncthreads();

        #pragma unroll
        for (int fn = 0; fn < 4; ++fn) {
            const int cc = wc + fn * 16 + l15;
            const float gb = gat_b[h * 128 + cc];
            #pragma unroll
            for (int fm = 0; fm < 2; ++fm) {
                #pragma unroll
                for (int rg = 0; rg < 4; ++rg) {
                    const int r = wr + fm * 16 + l4 * 4 + rg;
                    const unsigned short v = f2bf(eluf(a1[fm][fn][rg] + gb));
                    *(unsigned short*)(gtile + r * 256 + ((((cc >> 3) ^ (r & 7)) << 4) | ((cc & 7) << 1))) = v;
                }
            }
        }
        stage64<128>(mlpWT, 512, 0, 127, h * 128,      U,         t);
        stage64<128>(mlpWT, 512, 0, 127, h * 128 + 64, U + 16384, t);
        __syncthreads();

        #pragma unroll
        for (int ks = 0; ks < 4; ++ks) {
            const int s2 = ks >> 1, kk = ks & 1;
            const char* slab = U + s2 * 16384;
            bf16x8 af[2], bf[4];
            #pragma unroll
            for (int fm = 0; fm < 2; ++fm) {
                const int r2 = wr + fm * 16 + l15;
                const int chunk = (s2 * 8 + kk * 4 + l4) ^ (r2 & 7);
                af[fm] = *(const bf16x8*)(gtile + r2 * 256 + (chunk << 4));
            }
            const int koff = kk * 64 + l4 * 16;
            #pragma unroll
            for (int fn = 0; fn < 4; ++fn)
                bf[fn] = *(const bf16x8*)(slab + (wc + fn * 16 + l15) * 128 + (koff ^ rsw));
            #pragma unroll
            for (int fm = 0; fm < 2; ++fm)
                #pragma unroll
                for (int fn = 0; fn < 4; ++fn)
                    acc2[fm][fn] = __builtin_amdgcn_mfma_f32_16x16x32_bf16(af[fm], bf[fn], acc2[fm][fn], 0, 0, 0);
        }
        __syncthreads();
    }

    #pragma unroll
    for (int fn = 0; fn < 4; ++fn) {
        const int c = wc + fn * 16 + l15;
        const float sc = bng[c] * rsqrtf(bnv[c] + BN_EPS);
        const float sh = bnb[c] - bnm[c] * sc;
        const float mb = mlp_b[c];
        #pragma unroll
        for (int fm = 0; fm < 2; ++fm) {
            #pragma unroll
            for (int rg = 0; rg < 4; ++rg) {
                int r = bm + wr + fm * 16 + l4 * 4 + rg;
                if (r < NN)
                    x2[(size_t)r * 128 + c] += (acc2[fm][fn][rg] + mb) * sc + sh;
            }
        }
    }
}

// ---------------- sp_abs4 ----------------
__global__ void __launch_bounds__(256) sp_abs4(const int* __restrict__ off6,
                                               const int2* __restrict__ spp,
                                               const unsigned short* __restrict__ hb,
                                               unsigned short* __restrict__ tmp4) {
    const int y = blockIdx.y;
    const int* off = off6 + (y + 1) * (NN + 1);
    const int2* pk = spp + (size_t)(y + 1) * NE;
    unsigned short* out = tmp4 + (size_t)y * NN * 128;

    const int wid  = blockIdx.x * 4 + (threadIdx.x >> 6);
    const int lane = threadIdx.x & 63;
    const int co   = lane * 2;
    const int s0 = off[wid], s1 = off[wid + 1];
    float a0 = 0.f, a1 = 0.f;
    int j = s0;
    for (; j + 7 < s1; j += 8) {
        int2 e[8];
        unsigned v[8];
        #pragma unroll
        for (int q = 0; q < 8; ++q) e[q] = pk[j + q];
        #pragma unroll
        for (int q = 0; q < 8; ++q) v[q] = *(const unsigned*)(hb + (size_t)e[q].x * 128 + co);
        #pragma unroll
        for (int q = 0; q < 8; ++q) {
            float w = __int_as_float(e[q].y);
            a0 = fmaf(w, bf2f(v[q] & 0xffffu), a0);
            a1 = fmaf(w, bf2f(v[q] >> 16), a1);
        }
    }
    for (; j < s1; ++j) {
        int2 e = pk[j];
        float wj = __int_as_float(e.y);
        unsigned v = *(const unsigned*)(hb + (size_t)e.x * 128 + co);
        a0 = fmaf(wj, bf2f(v & 0xffffu), a0);
        a1 = fmaf(wj, bf2f(v >> 16), a1);
    }
    a0 = fabsf(a0); a1 = fabsf(a1);
    unsigned o = (unsigned)f2bf(a0) | ((unsigned)f2bf(a1) << 16);
    *(unsigned*)(out + (size_t)wid * 128 + co) = o;
}

// ---------------- sp_fused5 (tbl[5], 4-way) ----------------
__global__ void __launch_bounds__(256) sp_fused5(const int* __restrict__ off0,
                                                 const int2* __restrict__ spp0,
                                                 const unsigned short* __restrict__ hb,
                                                 const unsigned short* __restrict__ tmp4,
                                                 unsigned short* __restrict__ xcur5,
                                                 const float* __restrict__ watt,
                                                 float* __restrict__ as5,
                                                 float* __restrict__ ad5) {
    __shared__ float sWatt[5120];
    for (int i = threadIdx.x; i < 5120; i += 256) sWatt[i] = watt[i];
    __syncthreads();

    const int wid  = blockIdx.x * 4 + (threadIdx.x >> 6);
    const int lane = threadIdx.x & 63;
    const int co   = lane * 2;
    const int s0 = off0[wid], s1 = off0[wid + 1];
    const unsigned short* tbl[5] = {
        hb, tmp4, tmp4 + (size_t)1 * NN * 128, tmp4 + (size_t)2 * NN * 128, tmp4 + (size_t)3 * NN * 128 };

    float a[5][2] = {};
    int j = s0;
    for (; j + 3 < s1; j += 4) {
        int2 e0 = spp0[j], e1 = spp0[j + 1], e2 = spp0[j + 2], e3 = spp0[j + 3];
        size_t r0 = (size_t)e0.x * 128 + co, r1 = (size_t)e1.x * 128 + co;
        size_t r2 = (size_t)e2.x * 128 + co, r3 = (size_t)e3.x * 128 + co;
        unsigned v[5][4];
        #pragma unroll
        for (int y = 0; y < 5; ++y) {
            v[y][0] = *(const unsigned*)(tbl[y] + r0);
            v[y][1] = *(const unsigned*)(tbl[y] + r1);
            v[y][2] = *(const unsigned*)(tbl[y] + r2);
            v[y][3] = *(const unsigned*)(tbl[y] + r3);
        }
        float w0 = __int_as_float(e0.y), w1 = __int_as_float(e1.y);
        float w2 = __int_as_float(e2.y), w3 = __int_as_float(e3.y);
        #pragma unroll
        for (int y = 0; y < 5; ++y) {
            a[y][0] = fmaf(w0, bf2f(v[y][0] & 0xffffu), a[y][0]); a[y][1] = fmaf(w0, bf2f(v[y][0] >> 16), a[y][1]);
            a[y][0] = fmaf(w1, bf2f(v[y][1] & 0xffffu), a[y][0]); a[y][1] = fmaf(w1, bf2f(v[y][1] >> 16), a[y][1]);
            a[y][0] = fmaf(w2, bf2f(v[y][2] & 0xffffu), a[y][0]); a[y][1] = fmaf(w2, bf2f(v[y][2] >> 16), a[y][1]);
            a[y][0] = fmaf(w3, bf2f(v[y][3] & 0xffffu), a[y][0]); a[y][1] = fmaf(w3, bf2f(v[y][3] >> 16), a[y][1]);
        }
    }
    for (; j < s1; ++j) {
        int2 e = spp0[j];
        size_t r = (size_t)e.x * 128 + co;
        float wj = __int_as_float(e.y);
        #pragma unroll
        for (int y = 0; y < 5; ++y) {
            unsigned v = *(const unsigned*)(tbl[y] + r);
            a[y][0] = fmaf(wj, bf2f(v & 0xffffu), a[y][0]);
            a[y][1] = fmaf(wj, bf2f(v >> 16), a[y][1]);
        }
    }
    #pragma unroll
    for (int y = 0; y < 5; ++y) {
        unsigned o = (unsigned)f2bf(a[y][0]) | ((unsigned)f2bf(a[y][1]) << 16);
        *(unsigned*)(xcur5 + (size_t)y * NN * 128 + (size_t)wid * 128 + co) = o;
    }

    #pragma unroll
    for (int i = 0; i < 5; ++i) {
        #pragma unroll
        for (int h = 0; h < 4; ++h) {
            const float* wS = sWatt + ((i * 2 + 0) * 4 + h) * 128;
            const float* wD = sWatt + ((i * 2 + 1) * 4 + h) * 128;
            float ps = a[i][0] * wS[co] + a[i][1] * wS[co + 1];
            float pd = a[i][0] * wD[co] + a[i][1] * wD[co + 1];
            #pragma unroll
            for (int dd = 1; dd < 64; dd <<= 1) { ps += __shfl_xor(ps, dd); pd += __shfl_xor(pd, dd); }
            if (lane == 0) {
                as5[(size_t)i * NN * 4 + (size_t)wid * 4 + h] = ps;
                ad5[(size_t)i * NN * 4 + (size_t)wid * 4 + h] = pd;
            }
        }
    }
}

// ---------------- GAT aggregation, SINGLE-PASS softmax (no max-shift; scores are O(1)) ----------------
// alpha_j = exp(e_j)/Sum exp(e_j): accumulate unnormalized sum + den in ONE edge walk,
// divide at the end. den is computed redundantly per lane (no cross-lane reduce needed).
__device__ __forceinline__ void acc8(float* a, float al, uint4 v) {
    a[0] = fmaf(al, bf2f(v.x & 0xffffu), a[0]); a[1] = fmaf(al, bf2f(v.x >> 16), a[1]);
    a[2] = fmaf(al, bf2f(v.y & 0xffffu), a[2]); a[3] = fmaf(al, bf2f(v.y >> 16), a[3]);
    a[4] = fmaf(al, bf2f(v.z & 0xffffu), a[4]); a[5] = fmaf(al, bf2f(v.z >> 16), a[5]);
    a[6] = fmaf(al, bf2f(v.w & 0xffffu), a[6]); a[7] = fmaf(al, bf2f(v.w >> 16), a[7]);
}

__global__ void __launch_bounds__(256) gat_agg2(const int* __restrict__ goff, const int* __restrict__ gsrc,
                                                const float* __restrict__ as_, const float* __restrict__ ad_,
                                                const unsigned short* __restrict__ xcur,
                                                unsigned short* __restrict__ agg) {
    const int wid  = blockIdx.x * 4 + (threadIdx.x >> 6);
    const int lane = threadIdx.x & 63;
    const int hd   = lane >> 4;
    const int cl   = (lane & 15) * 8;
    const int s0 = goff[wid], s1 = goff[wid + 1];
    const float advh = ad_[(size_t)wid * 4 + hd];

    float den = 0.f;
    float ac[8] = {};
    int j = s0;
    for (; j + 3 < s1; j += 4) {
        int i0 = gsrc[j], i1 = gsrc[j + 1], i2 = gsrc[j + 2], i3 = gsrc[j + 3];
        float q0 = as_[(size_t)i0 * 4 + hd], q1 = as_[(size_t)i1 * 4 + hd];
        float q2 = as_[(size_t)i2 * 4 + hd], q3 = as_[(size_t)i3 * 4 + hd];
        uint4 v0 = *(const uint4*)(xcur + (size_t)i0 * 128 + cl);
        uint4 v1 = *(const uint4*)(xcur + (size_t)i1 * 128 + cl);
        uint4 v2 = *(const uint4*)(xcur + (size_t)i2 * 128 + cl);
        uint4 v3 = *(const uint4*)(xcur + (size_t)i3 * 128 + cl);
        float w0 = __expf(lrelu02(q0 + advh));
        float w1 = __expf(lrelu02(q1 + advh));
        float w2 = __expf(lrelu02(q2 + advh));
        float w3 = __expf(lrelu02(q3 + advh));
        den += w0 + w1 + w2 + w3;
        acc8(ac, w0, v0); acc8(ac, w1, v1); acc8(ac, w2, v2); acc8(ac, w3, v3);
    }
    for (; j < s1; ++j) {
        int si = gsrc[j];
        float q = as_[(size_t)si * 4 + hd];
        uint4 v = *(const uint4*)(xcur + (size_t)si * 128 + cl);
        float w = __expf(lrelu02(q + advh));
        den += w;
        acc8(ac, w, v);
    }
    const float inv = 1.f / (den + 1e-16f);
    uint4 ov;
    ov.x = (unsigned)f2bf(ac[0] * inv) | ((unsigned)f2bf(ac[1] * inv) << 16);
    ov.y = (unsigned)f2bf(ac[2] * inv) | ((unsigned)f2bf(ac[3] * inv) << 16);
    ov.z = (unsigned)f2bf(ac[4] * inv) | ((unsigned)f2bf(ac[5] * inv) << 16);
    ov.w = (unsigned)f2bf(ac[6] * inv) | ((unsigned)f2bf(ac[7] * inv) << 16);
    *(uint4*)(agg + (size_t)wid * 512 + hd * 128 + cl) = ov;
}

// ---------------- final ----------------
__global__ void __launch_bounds__(256) final_out(const float* __restrict__ x2,
                                                 const float* __restrict__ bn0g, const float* __restrict__ bn0b,
                                                 const float* __restrict__ bn0m, const float* __restrict__ bn0v,
                                                 const float* __restrict__ outW, const float* __restrict__ outb,
                                                 float* __restrict__ out) {
    __shared__ float sW[128 * 12];
    __shared__ float sSc[128], sSh[128];
    for (int i = threadIdx.x; i < 1280; i += 256) {
        int r = i / 10, c = i - r * 10;
        sW[r * 12 + c] = outW[i];
    }
    if (threadIdx.x < 128) {
        int c = threadIdx.x;
        float sc = bn0g[c] * rsqrtf(bn0v[c] + BN_EPS);
        sSc[c] = sc;
        sSh[c] = bn0b[c] - bn0m[c] * sc;
    }
    __syncthreads();
    const int wid  = blockIdx.x * 4 + (threadIdx.x >> 6);
    const int lane = threadIdx.x & 63;
    const int c0 = lane * 2;
    float2 a = *(const float2*)(x2 + (size_t)wid * 128 + c0);
    float a0 = eluf(a.x * sSc[c0] + sSh[c0]);
    float a1 = eluf(a.y * sSc[c0 + 1] + sSh[c0 + 1]);
    float p[NCLS];
    #pragma unroll
    for (int j = 0; j < NCLS; ++j)
        p[j] = a0 * sW[c0 * 12 + j] + a1 * sW[(c0 + 1) * 12 + j];
    #pragma unroll
    for (int j = 0; j < NCLS; ++j) {
        float v = p[j];
        v += __shfl_xor(v, 1);  v += __shfl_xor(v, 2);  v += __shfl_xor(v, 4);
        v += __shfl_xor(v, 8);  v += __shfl_xor(v, 16); v += __shfl_xor(v, 32);
        p[j] = v;
    }
    float z[NCLS];
    #pragma unroll
    for (int j = 0; j < NCLS; ++j) z[j] = p[j] + outb[j];
    float m = z[0];
    #pragma unroll
    for (int j = 1; j < NCLS; ++j) m = fmaxf(m, z[j]);
    float ssum = 0.f;
    #pragma unroll
    for (int j = 0; j < NCLS; ++j) ssum += __expf(z[j] - m);
    float lse = m + __logf(ssum);
    #pragma unroll
    for (int j = 0; j < NCLS; ++j)
        if (lane == j) out[(size_t)wid * NCLS + j] = z[j] - lse;
}

// ---------------- launcher ----------------
extern "C" void kernel_launch(void* const* d_in, const int* in_sizes, int n_in,
                              void* d_out, int out_size, void* d_ws, size_t ws_size,
                              hipStream_t stream) {
    const float* x        = (const float*)d_in[0];
    const int*   edge_ix  = (const int*)  d_in[1];
    const int*   scat_idx = (const int*)  d_in[2];
    const float* scat_w   = (const float*)d_in[3];
    const float* lin_W    = (const float*)d_in[4];
    const float* lin_b    = (const float*)d_in[5];
    const float* gat_W    = (const float*)d_in[6];
    const float* att_src  = (const float*)d_in[7];
    const float* att_dst  = (const float*)d_in[8];
    const float* gat_b    = (const float*)d_in[9];
    const float* mlp_W    = (const float*)d_in[10];
    const float* mlp_b    = (const float*)d_in[11];
    const float* bn_g     = (const float*)d_in[12];
    const float* bn_b     = (const float*)d_in[13];
    const float* bn_m     = (const float*)d_in[14];
    const float* bn_v     = (const float*)d_in[15];
    const float* bn0_g    = (const float*)d_in[16];
    const float* bn0_b    = (const float*)d_in[17];
    const float* bn0_m    = (const float*)d_in[18];
    const float* bn0_v    = (const float*)d_in[19];
    const float* out_W    = (const float*)d_in[20];
    const float* out_b    = (const float*)d_in[21];
    float* out = (float*)d_out;

    char* ws = (char*)d_ws;
    unsigned short* xb    = (unsigned short*)(ws + OFF_U1);
    unsigned short* xcur5 = (unsigned short*)(ws + OFF_U1);
    unsigned short* hb    = (unsigned short*)(ws + OFF_HB);
    float*          x2    = (float*)(ws + OFF_X2);
    unsigned short* agg   = (unsigned short*)(ws + OFF_AGG);
    unsigned short* tmp4  = (unsigned short*)(ws + OFF_GOUT);
    int2*  stg_sp = (int2*)(ws + OFF_GOUT);
    int*   stg_g  = (int*)(ws + OFF_GOUT + (size_t)NSETS * NE * 8);
    unsigned short* wt    = (unsigned short*)(ws + OFF_WT);
    unsigned short* linWT = wt;
    unsigned short* gatWT = wt + 65536;
    unsigned short* mlpWT = wt + 65536 * 6;
    float* watt   = (float*)(ws + OFF_WATT);
    int*   off6   = (int*)(ws + OFF_OFF6);
    int2*  spp    = (int2*)(ws + OFF_SPP);
    int*   g_src  = (int*)(ws + OFF_GSRC);
    int*   bh     = (int*)(ws + OFF_CNT);
    int*   bb     = bh + NBLK_SORT * NWGMAX;
    float* as5    = (float*)(ws + OFF_AS5);
    float* ad5    = (float*)(ws + OFF_AD5);

    const dim3 b256(256);
    const int* goff = off6 + 5 * (NN + 1);

    // ---- CSR build + dtype prep ----
    prep1<<<PREP_GRID, b256, 0, stream>>>(scat_idx, edge_ix, bh, x, xb,
                                          lin_W, gat_W, mlp_W, linWT, gatWT, mlpWT,
                                          att_src, att_dst, watt);
    bktscan<<<6, 128, 0, stream>>>(bh, bb, off6);
    wgscan<<<NBLK_SORT, 128, 0, stream>>>(bb, bh);
    binlin<<<LIN_B + NBLK_BIN, b256, 0, stream>>>(scat_idx, scat_w, edge_ix, bh, stg_sp, stg_g,
                                                  xb, linWT, lin_b, hb, x2);
    sortP<<<NBLK_SORT, b256, 0, stream>>>(bb, stg_sp, stg_g, spp, g_src, off6);

    // ---- solo passes (+ fused attention scores) ----
    sp_abs4<<<dim3(7500, 4), b256, 0, stream>>>(off6, spp, hb, tmp4);
    sp_fused5<<<7500, b256, 0, stream>>>(off6, spp, hb, tmp4, xcur5, watt, as5, ad5);

    // ---- 5 GAT branches ----
    for (int i = 0; i < NSETS; ++i) {
        gat_agg2<<<7500, b256, 0, stream>>>(goff, g_src,
                                            as5 + (size_t)i * NN * 4, ad5 + (size_t)i * NN * 4,
                                            xcur5 + (size_t)i * NN * 128, agg);
        fusedGM<<<469, b256, 0, stream>>>(agg, gatWT + (size_t)i * 65536, mlpWT + (size_t)i * 65536,
                                          gat_b + (size_t)i * 512, mlp_b + (size_t)i * 128,
                                          bn_g + (size_t)i * 128, bn_b + (size_t)i * 128,
                                          bn_m + (size_t)i * 128, bn_v + (size_t)i * 128, x2);
    }

    // ---- final ----
    final_out<<<7500, b256, 0, stream>>>(x2, bn0_g, bn0_b, bn0_m, bn0_v, out_W, out_b, out);
}